// Round 9
// baseline (524.977 us; speedup 1.0000x reference)
//
#include <hip/hip_runtime.h>

#define N_NODES 100000
#define N_EDGES 1600000

#define MEMFENCE asm volatile("" ::: "memory")

typedef __attribute__((ext_vector_type(8))) short bf16x8;
typedef __attribute__((ext_vector_type(4))) float f32x4;

__device__ __forceinline__ unsigned short f2bf(float f) {
    unsigned u = __float_as_uint(f);
    u = (u + 0x7FFFu + ((u >> 16) & 1u)) >> 16;
    return (unsigned short)u;
}
__device__ __forceinline__ float bf2f(unsigned short h) {
    return __uint_as_float(((unsigned)h) << 16);
}
__device__ __forceinline__ float bflo(unsigned w) { return __uint_as_float(w << 16); }
__device__ __forceinline__ float bfhi(unsigned w) { return __uint_as_float(w & 0xFFFF0000u); }

__device__ __forceinline__ bf16x8 ld_frag(const unsigned short* p) {
    return *(const bf16x8*)p;
}

// ---------------------------------------------------------------------------
// CSR row_ptr via binary search over sorted edge_row
// ---------------------------------------------------------------------------
__global__ void build_row_ptr(const int* __restrict__ row, int* __restrict__ rp) {
    int n = blockIdx.x * blockDim.x + threadIdx.x;
    if (n > N_NODES) return;
    int lo = 0, hi = N_EDGES;
    while (lo < hi) {
        int mid = (lo + hi) >> 1;
        if (row[mid] < n) lo = mid + 1; else hi = mid;
    }
    rp[n] = lo;
}

// ---------------------------------------------------------------------------
// x (fp32, 100k x 100) -> bf16 padded to ld 104
// ---------------------------------------------------------------------------
__global__ __launch_bounds__(256) void conv_x(const float* __restrict__ x,
                                              unsigned short* __restrict__ xb) {
    const int total = N_NODES * 104;
    for (int i = blockIdx.x * 256 + threadIdx.x; i < total; i += gridDim.x * 256) {
        int r = i / 104, c = i - r * 104;
        xb[i] = (c < 100) ? f2bf(x[(size_t)r * 100 + c]) : (unsigned short)0;
    }
}

// ---------------------------------------------------------------------------
// All weight prep in ONE kernel
// ---------------------------------------------------------------------------
__global__ __launch_bounds__(256) void prep_all(
    const float* __restrict__ gc0W, const float* __restrict__ gc0Ws,
    const float* __restrict__ gc1W, const float* __restrict__ gc1Ws,
    const float* __restrict__ gc2W, const float* __restrict__ gc2Ws,
    const float* __restrict__ f1W,  const float* __restrict__ f2aW,
    const float* __restrict__ f2bW,
    const float* __restrict__ gc0b, const float* __restrict__ gc0bs,
    const float* __restrict__ gc2b, const float* __restrict__ gc2bs,
    const float* __restrict__ gc1b, const float* __restrict__ gc1bs,
    unsigned short* __restrict__ Bt0, unsigned short* __restrict__ Bt1,
    unsigned short* __restrict__ Bt2, unsigned short* __restrict__ Btf1,
    unsigned short* __restrict__ Btf2a, unsigned short* __restrict__ Btf2b,
    float* __restrict__ bias0, float* __restrict__ bias2, float* __restrict__ bias1)
{
    int i = blockIdx.x * 256 + threadIdx.x;
    if (i < 44800) {  // Bt0: concat-K (K=100,Kpad=104), N=200, ldk=224
        int n = i / 224, k = i - n * 224; float v = 0.f;
        if (k < 104) { if (k < 100) v = gc0W[(size_t)k * 200 + n]; }
        else { int kr = k - 104; if (kr < 100) v = gc0Ws[(size_t)kr * 200 + n]; }
        Bt0[i] = f2bf(v); return;
    }
    i -= 44800;
    if (i < 57344) {  // Bt1: side-by-side N (K=200, N0=128, N=256), ldk=224
        int n = i / 224, k = i - n * 224; float v = 0.f;
        if (k < 200) v = (n < 128) ? gc1W[(size_t)k * 128 + n] : gc1Ws[(size_t)k * 128 + (n - 128)];
        Bt1[i] = f2bf(v); return;
    }
    i -= 57344;
    if (i < 32768) {  // Bt2: concat-K (K=128), N=128, ldk=256
        int n = i / 256, k = i - n * 256; float v;
        if (k < 128) v = gc2W[(size_t)k * 128 + n];
        else         v = gc2Ws[(size_t)(k - 128) * 128 + n];
        Bt2[i] = f2bf(v); return;
    }
    i -= 32768;
    if (i < 16384) { int n = i >> 7, k = i & 127; Btf1[i] = f2bf(f1W[(size_t)k * 128 + n]); return; }
    i -= 16384;
    if (i < 32768) { int n = i >> 7, k = i & 127; Btf2a[i] = f2bf(f2aW[(size_t)k * 256 + n]); return; }
    i -= 32768;
    if (i < 4608) { int n = i >> 8, k = i & 255; Btf2b[i] = f2bf(f2bW[(size_t)k * 18 + n]); return; }
    i -= 4608;
    if (i < 200) { bias0[i] = gc0b[i] + gc0bs[i]; return; }
    i -= 200;
    if (i < 128) { bias2[i] = gc2b[i] + gc2bs[i]; return; }
    i -= 128;
    if (i < 128) { bias1[i] = gc1b[i] + gc1bs[i]; return; }
}

// ---------------------------------------------------------------------------
// SpMM v5: 16 lanes per node (uint4 = 8 features/lane), 4 nodes/wave,
// 8 edges in flight per node. FUSE=1: out = relu(agg + z + b01), z at +128.
// ---------------------------------------------------------------------------
template<int FUSE>
__global__ __launch_bounds__(256) void spmm_v5(
    const unsigned short* __restrict__ xin, int ldin, int F,
    const int* __restrict__ rp, const int* __restrict__ col,
    const float* __restrict__ val, const float* __restrict__ b01,
    unsigned short* __restrict__ outp, int ldout)
{
    const int node = blockIdx.x * 16 + (threadIdx.x >> 4);
    const int l16 = threadIdx.x & 15;
    const int f8 = l16 * 8;
    const bool act = f8 < F;
    const int e0 = rp[node], e1 = rp[node + 1];
    const unsigned short* xf = xin + f8;

    float a[8];
#pragma unroll
    for (int k = 0; k < 8; k++) a[k] = 0.f;

    for (int e = e0; e < e1; e += 8) {
        int   cj[8]; float vj[8];
#pragma unroll
        for (int j = 0; j < 8; j++) {
            int ej = e + j;
            bool m = ej < e1;
            int es = m ? ej : e0;
            cj[j] = col[es];
            float vv = val[es];
            vj[j] = m ? vv : 0.f;
        }
        if (act) {
            uint4 u[8];
#pragma unroll
            for (int j = 0; j < 8; j++)
                u[j] = *(const uint4*)(xf + (size_t)cj[j] * ldin);
#pragma unroll
            for (int j = 0; j < 8; j++) {
                float v = vj[j];
                a[0] += v * bflo(u[j].x); a[1] += v * bfhi(u[j].x);
                a[2] += v * bflo(u[j].y); a[3] += v * bfhi(u[j].y);
                a[4] += v * bflo(u[j].z); a[5] += v * bfhi(u[j].z);
                a[6] += v * bflo(u[j].w); a[7] += v * bfhi(u[j].w);
            }
        }
    }

    if (act) {
        if (FUSE) {
            uint4 uz = *(const uint4*)(xin + (size_t)node * ldin + 128 + f8);
            float z[8] = {bflo(uz.x), bfhi(uz.x), bflo(uz.y), bfhi(uz.y),
                          bflo(uz.z), bfhi(uz.z), bflo(uz.w), bfhi(uz.w)};
#pragma unroll
            for (int k = 0; k < 8; k++)
                a[k] = fmaxf(a[k] + z[k] + b01[f8 + k], 0.f);
        }
        uint4 pk;
        pk.x = ((unsigned)f2bf(a[1]) << 16) | (unsigned)f2bf(a[0]);
        pk.y = ((unsigned)f2bf(a[3]) << 16) | (unsigned)f2bf(a[2]);
        pk.z = ((unsigned)f2bf(a[5]) << 16) | (unsigned)f2bf(a[4]);
        pk.w = ((unsigned)f2bf(a[7]) << 16) | (unsigned)f2bf(a[6]);
        *(uint4*)(outp + (size_t)node * ldout + f8) = pk;
    }
}

// ---------------------------------------------------------------------------
// FUSED HEAD v5: B preloaded to registers (chunked) + memory fences.
//   h0 = relu([agg0|xb] @ Bt0 + bias0)  (K=208/pad224, N=200, LDS-resident)
//   yz = h0 @ Bt1                       (K=224, N=256)
// wave w: 64 rows x cols [64w, 64w+64)
// ---------------------------------------------------------------------------
__global__ __launch_bounds__(256) void gemm_head(
    const unsigned short* __restrict__ agg0, const unsigned short* __restrict__ xb,
    const unsigned short* __restrict__ Bt0, const float* __restrict__ bias0,
    const unsigned short* __restrict__ Bt1,
    unsigned short* __restrict__ yz, int M)
{
    __shared__ __align__(16) unsigned short H[64][264];

    const int tid = threadIdx.x;
    const int rowBase = blockIdx.x * 64;
    const int wave = tid >> 6, lane = tid & 63;
    const int cb = wave * 64;
    const int lrow = lane & 15, lq = lane >> 4;
    const int kq = lq * 8;

    // ---------------- stage 1: h0 = relu([agg0|xb]@Bt0 + bias0) ----------
    {
        f32x4 acc[4][4] = {};
        // ---- chunk 0: ki 0..3 ----
        {
            bf16x8 Bf[4][4];
#pragma unroll
            for (int ki = 0; ki < 4; ++ki)
#pragma unroll
                for (int n = 0; n < 4; ++n) {
                    int nr = cb + 16 * n + lrow;
                    bf16x8 t = {};
                    if (nr < 200) t = ld_frag(Bt0 + (size_t)nr * 224 + 32 * ki + kq);
                    Bf[ki][n] = t;
                }
            MEMFENCE;
            bf16x8 A2[2][4];
#pragma unroll
            for (int m = 0; m < 4; ++m) {
                int gr = rowBase + 16 * m + lrow;
                bf16x8 t = {};
                if (gr < M)
                    t = (kq < 104) ? ld_frag(agg0 + (size_t)gr * 104 + kq)
                                   : ld_frag(xb   + (size_t)gr * 104 + (kq - 104));
                A2[0][m] = t;
            }
            MEMFENCE;
#pragma unroll
            for (int ki = 0; ki < 4; ++ki) {
                const int cur = ki & 1;
                if (ki < 3) {
                    int k0 = 32 * (ki + 1) + kq;
#pragma unroll
                    for (int m = 0; m < 4; ++m) {
                        int gr = rowBase + 16 * m + lrow;
                        bf16x8 t = {};
                        if (gr < M)
                            t = (k0 < 104) ? ld_frag(agg0 + (size_t)gr * 104 + k0)
                                           : ld_frag(xb   + (size_t)gr * 104 + (k0 - 104));
                        A2[cur ^ 1][m] = t;
                    }
                }
                MEMFENCE;
#pragma unroll
                for (int m = 0; m < 4; ++m)
#pragma unroll
                    for (int n = 0; n < 4; ++n)
                        acc[m][n] = __builtin_amdgcn_mfma_f32_16x16x32_bf16(A2[cur][m], Bf[ki][n], acc[m][n], 0, 0, 0);
            }
        }
        // ---- chunk 1: ki 4..6 ----
        {
            bf16x8 Bf[3][4];
#pragma unroll
            for (int ki = 0; ki < 3; ++ki)
#pragma unroll
                for (int n = 0; n < 4; ++n) {
                    int nr = cb + 16 * n + lrow;
                    bf16x8 t = {};
                    if (nr < 200) t = ld_frag(Bt0 + (size_t)nr * 224 + 32 * (ki + 4) + kq);
                    Bf[ki][n] = t;
                }
            MEMFENCE;
            bf16x8 A2[2][4];
#pragma unroll
            for (int m = 0; m < 4; ++m) {
                int gr = rowBase + 16 * m + lrow;
                int k0 = 128 + kq;
                bf16x8 t = {};
                if (gr < M && k0 < 208)
                    t = ld_frag(xb + (size_t)gr * 104 + (k0 - 104));
                A2[0][m] = t;
            }
            MEMFENCE;
#pragma unroll
            for (int ki = 0; ki < 3; ++ki) {
                const int cur = ki & 1;
                if (ki < 2) {
                    int k0 = 32 * (ki + 5) + kq;
#pragma unroll
                    for (int m = 0; m < 4; ++m) {
                        int gr = rowBase + 16 * m + lrow;
                        bf16x8 t = {};
                        if (gr < M && k0 < 208)
                            t = ld_frag(xb + (size_t)gr * 104 + (k0 - 104));
                        A2[cur ^ 1][m] = t;
                    }
                }
                MEMFENCE;
#pragma unroll
                for (int m = 0; m < 4; ++m)
#pragma unroll
                    for (int n = 0; n < 4; ++n)
                        acc[m][n] = __builtin_amdgcn_mfma_f32_16x16x32_bf16(A2[cur][m], Bf[ki][n], acc[m][n], 0, 0, 0);
            }
        }
#pragma unroll
        for (int n = 0; n < 4; ++n) {
            int colg = cb + 16 * n + lrow;
            if (colg >= 224) continue;
            float bb = (colg < 200) ? bias0[colg] : 0.f;
#pragma unroll
            for (int m = 0; m < 4; ++m)
#pragma unroll
                for (int r = 0; r < 4; ++r) {
                    int rowl = 16 * m + lq * 4 + r;
                    H[rowl][colg] = f2bf(fmaxf(acc[m][n][r] + bb, 0.f));
                }
        }
    }
    __syncthreads();

    // ---------------- stage 2: yz = h0 @ Bt1 (A from LDS, B preloaded) ------
    {
        f32x4 acc[4][4] = {};
        {
            bf16x8 Bf[4][4];
#pragma unroll
            for (int ki = 0; ki < 4; ++ki)
#pragma unroll
                for (int n = 0; n < 4; ++n)
                    Bf[ki][n] = ld_frag(Bt1 + (size_t)(cb + 16 * n + lrow) * 224 + 32 * ki + kq);
            MEMFENCE;
#pragma unroll
            for (int ki = 0; ki < 4; ++ki) {
                bf16x8 af[4];
#pragma unroll
                for (int m = 0; m < 4; ++m) af[m] = *(const bf16x8*)&H[16 * m + lrow][32 * ki + kq];
#pragma unroll
                for (int m = 0; m < 4; ++m)
#pragma unroll
                    for (int n = 0; n < 4; ++n)
                        acc[m][n] = __builtin_amdgcn_mfma_f32_16x16x32_bf16(af[m], Bf[ki][n], acc[m][n], 0, 0, 0);
            }
        }
        {
            bf16x8 Bf[3][4];
#pragma unroll
            for (int ki = 0; ki < 3; ++ki)
#pragma unroll
                for (int n = 0; n < 4; ++n)
                    Bf[ki][n] = ld_frag(Bt1 + (size_t)(cb + 16 * n + lrow) * 224 + 32 * (ki + 4) + kq);
            MEMFENCE;
#pragma unroll
            for (int ki = 0; ki < 3; ++ki) {
                bf16x8 af[4];
#pragma unroll
                for (int m = 0; m < 4; ++m) af[m] = *(const bf16x8*)&H[16 * m + lrow][32 * (ki + 4) + kq];
#pragma unroll
                for (int m = 0; m < 4; ++m)
#pragma unroll
                    for (int n = 0; n < 4; ++n)
                        acc[m][n] = __builtin_amdgcn_mfma_f32_16x16x32_bf16(af[m], Bf[ki][n], acc[m][n], 0, 0, 0);
            }
        }
        __syncthreads();   // all H reads done before overwrite
#pragma unroll
        for (int n = 0; n < 4; ++n) {
            int colg = cb + 16 * n + lrow;
#pragma unroll
            for (int m = 0; m < 4; ++m)
#pragma unroll
                for (int r = 0; r < 4; ++r) {
                    int rowl = 16 * m + lq * 4 + r;
                    H[rowl][colg] = f2bf(acc[m][n][r]);
                }
        }
    }
    __syncthreads();
    // ---------------- coalesced store: 64 rows x 256 cols, uint4/thread ------
#pragma unroll
    for (int i = 0; i < 8; ++i) {
        int c = tid + 256 * i;           // 0..2047
        int row = c >> 5;                // 0..63
        int ch  = c & 31;                // 0..31 (x8 elements)
        int rowg = rowBase + row;
        if (rowg < M)
            *(uint4*)(yz + (size_t)rowg * 256 + ch * 8) = *(const uint4*)&H[row][ch * 8];
    }
}

// ---------------------------------------------------------------------------
// FUSED TAIL v5: B fully preloaded to registers per stage + memory fences.
//   h2 = relu([agg2|h1]@Bt2 + bias2)  (K=256, N=128; wave -> 32 cols)
//   h3 = relu(h2@Btf1 + fc1_b)        (K=128, N=128)
//   h4 = h3@Btf2a + fc2a_b            (K=128, N=256; wave -> 64 cols)
//   + BN column partials via shfl + global atomics
// ---------------------------------------------------------------------------
__global__ __launch_bounds__(256) void gemm_tail(
    const unsigned short* __restrict__ agg2, const unsigned short* __restrict__ h1,
    const unsigned short* __restrict__ Bt2, const float* __restrict__ bias2,
    const unsigned short* __restrict__ Btf1, const float* __restrict__ fc1b,
    const unsigned short* __restrict__ Btf2a, const float* __restrict__ fc2ab,
    unsigned short* __restrict__ h4, float* __restrict__ stats, int M)
{
    __shared__ __align__(16) unsigned short H[64][264];

    const int tid = threadIdx.x;
    const int rowBase = blockIdx.x * 64;
    const int wave = tid >> 6, lane = tid & 63;
    const int lrow = lane & 15, lq = lane >> 4;
    const int kq = lq * 8;

    // ---------------- stage 1: h2 = relu([agg2|h1]@Bt2 + bias2) -------------
    {
        const int cb = wave * 32;
        f32x4 acc[4][2] = {};
        bf16x8 Bf[8][2];
#pragma unroll
        for (int ki = 0; ki < 8; ++ki)
#pragma unroll
            for (int n = 0; n < 2; ++n)
                Bf[ki][n] = ld_frag(Bt2 + (size_t)(cb + 16 * n + lrow) * 256 + 32 * ki + kq);
        MEMFENCE;
        bf16x8 A2[2][4];
#pragma unroll
        for (int m = 0; m < 4; ++m) {
            int gr = rowBase + 16 * m + lrow;
            bf16x8 t = {};
            if (gr < M) t = ld_frag(agg2 + (size_t)gr * 128 + kq);
            A2[0][m] = t;
        }
        MEMFENCE;
#pragma unroll
        for (int ki = 0; ki < 8; ++ki) {
            const int cur = ki & 1;
            if (ki < 7) {
                const int kin = ki + 1;
                int k0 = 32 * kin + kq;
                const unsigned short* Asrc = (kin < 4) ? agg2 : h1;
                int krel = (kin < 4) ? k0 : k0 - 128;
#pragma unroll
                for (int m = 0; m < 4; ++m) {
                    int gr = rowBase + 16 * m + lrow;
                    bf16x8 t = {};
                    if (gr < M) t = ld_frag(Asrc + (size_t)gr * 128 + krel);
                    A2[cur ^ 1][m] = t;
                }
            }
            MEMFENCE;
#pragma unroll
            for (int m = 0; m < 4; ++m)
#pragma unroll
                for (int n = 0; n < 2; ++n)
                    acc[m][n] = __builtin_amdgcn_mfma_f32_16x16x32_bf16(A2[cur][m], Bf[ki][n], acc[m][n], 0, 0, 0);
        }
#pragma unroll
        for (int n = 0; n < 2; ++n) {
            int colg = cb + 16 * n + lrow;
            float bb = bias2[colg];
#pragma unroll
            for (int m = 0; m < 4; ++m)
#pragma unroll
                for (int r = 0; r < 4; ++r) {
                    int rowl = 16 * m + lq * 4 + r;
                    H[rowl][colg] = f2bf(fmaxf(acc[m][n][r] + bb, 0.f));
                }
        }
    }
    __syncthreads();

    // ---------------- stage 2: h3 = relu(h2@Btf1 + fc1_b) ----------------
    {
        const int cb = wave * 32;
        f32x4 acc[4][2] = {};
        bf16x8 Bf[4][2];
#pragma unroll
        for (int ki = 0; ki < 4; ++ki)
#pragma unroll
            for (int n = 0; n < 2; ++n)
                Bf[ki][n] = ld_frag(Btf1 + (size_t)(cb + 16 * n + lrow) * 128 + 32 * ki + kq);
        MEMFENCE;
#pragma unroll
        for (int ki = 0; ki < 4; ++ki) {
            bf16x8 af[4];
#pragma unroll
            for (int m = 0; m < 4; ++m) af[m] = *(const bf16x8*)&H[16 * m + lrow][32 * ki + kq];
#pragma unroll
            for (int m = 0; m < 4; ++m)
#pragma unroll
                for (int n = 0; n < 2; ++n)
                    acc[m][n] = __builtin_amdgcn_mfma_f32_16x16x32_bf16(af[m], Bf[ki][n], acc[m][n], 0, 0, 0);
        }
        __syncthreads();   // all reads of h2 done before overwrite
#pragma unroll
        for (int n = 0; n < 2; ++n) {
            int colg = cb + 16 * n + lrow;
            float bb = fc1b[colg];
#pragma unroll
            for (int m = 0; m < 4; ++m)
#pragma unroll
                for (int r = 0; r < 4; ++r) {
                    int rowl = 16 * m + lq * 4 + r;
                    H[rowl][colg] = f2bf(fmaxf(acc[m][n][r] + bb, 0.f));
                }
        }
    }
    __syncthreads();

    // ---------------- stage 3: h4 = h3@Btf2a + fc2a_b + BN partials ----------
    {
        const int cb = wave * 64;
        f32x4 acc[4][4] = {};
        bf16x8 Bf[4][4];
#pragma unroll
        for (int ki = 0; ki < 4; ++ki)
#pragma unroll
            for (int n = 0; n < 4; ++n)
                Bf[ki][n] = ld_frag(Btf2a + (size_t)(cb + 16 * n + lrow) * 128 + 32 * ki + kq);
        MEMFENCE;
#pragma unroll
        for (int ki = 0; ki < 4; ++ki) {
            bf16x8 af[4];
#pragma unroll
            for (int m = 0; m < 4; ++m) af[m] = *(const bf16x8*)&H[16 * m + lrow][32 * ki + kq];
#pragma unroll
            for (int m = 0; m < 4; ++m)
#pragma unroll
                for (int n = 0; n < 4; ++n)
                    acc[m][n] = __builtin_amdgcn_mfma_f32_16x16x32_bf16(af[m], Bf[ki][n], acc[m][n], 0, 0, 0);
        }
        __syncthreads();   // all H (h3) reads done before overwrite

#pragma unroll
        for (int n = 0; n < 4; ++n) {
            int colg = cb + 16 * n + lrow;
            float bb = fc2ab[colg];
            float s = 0.f, s2 = 0.f;
#pragma unroll
            for (int m = 0; m < 4; ++m)
#pragma unroll
                for (int r = 0; r < 4; ++r) {
                    int rowl = 16 * m + lq * 4 + r;
                    float v = acc[m][n][r] + bb;
                    H[rowl][colg] = f2bf(v);
                    if (rowBase + rowl < M) { s += v; s2 += v * v; }
                }
            // reduce over the 4 lanes (lq=0..3) sharing this column
            s  += __shfl_xor(s, 16);  s  += __shfl_xor(s, 32);
            s2 += __shfl_xor(s2, 16); s2 += __shfl_xor(s2, 32);
            if (lq == 0) {
                atomicAdd(&stats[colg], s);
                atomicAdd(&stats[256 + colg], s2);
            }
        }
        __syncthreads();
        // coalesced h4 store
#pragma unroll
        for (int i = 0; i < 8; ++i) {
            int c = tid + 256 * i;
            int row = c >> 5;
            int ch  = c & 31;
            int rowg = rowBase + row;
            if (rowg < M)
                *(uint4*)(h4 + (size_t)rowg * 256 + ch * 8) = *(const uint4*)&H[row][ch * 8];
        }
    }
}

__global__ void bn_finalize(float* __restrict__ stats,
                            const float* __restrict__ g,
                            const float* __restrict__ b) {
    int t = threadIdx.x;
    const float invN = 1.f / (float)N_NODES;
    float mu = stats[t] * invN;
    float var = stats[256 + t] * invN - mu * mu;
    float sc = g[t] * rsqrtf(var + 1e-5f);
    stats[512 + t] = sc;
    stats[768 + t] = b[t] - mu * sc;
}

// ---------------------------------------------------------------------------
// fc2b v2: out = BNrelu(h4) @ Btf2b + fc2b_b (K=256, N=18), B preloaded,
// A 1-deep dbuf with fences. Zero LDS/barriers.
// ---------------------------------------------------------------------------
__global__ __launch_bounds__(256) void fc2b_kernel(
    const unsigned short* __restrict__ h4, const unsigned short* __restrict__ Btf2b,
    const float* __restrict__ bias, const float* __restrict__ stats,
    float* __restrict__ out, int M)
{
    const int tid = threadIdx.x;
    const int wave = tid >> 6, lane = tid & 63;
    const int lrow = lane & 15, lq = lane >> 4;
    const int kq = lq * 8;
    const int rowBase = blockIdx.x * 128 + wave * 32;

    f32x4 acc[2][2] = {};
    bf16x8 Bf[8][2];
#pragma unroll
    for (int ki = 0; ki < 8; ++ki)
#pragma unroll
        for (int n = 0; n < 2; ++n) {
            int nr = 16 * n + lrow;
            bf16x8 t = {};
            if (nr < 18) t = ld_frag(Btf2b + (size_t)nr * 256 + 32 * ki + kq);
            Bf[ki][n] = t;
        }
    MEMFENCE;
    uint4 ub[2][2];
#pragma unroll
    for (int m = 0; m < 2; ++m) {
        int gr = rowBase + 16 * m + lrow;
        uint4 u = make_uint4(0, 0, 0, 0);
        if (gr < M) u = *(const uint4*)(h4 + (size_t)gr * 256 + kq);
        ub[0][m] = u;
    }
    MEMFENCE;
#pragma unroll
    for (int ki = 0; ki < 8; ++ki) {
        const int cur = ki & 1;
        if (ki < 7) {
            int k0 = 32 * (ki + 1) + kq;
#pragma unroll
            for (int m = 0; m < 2; ++m) {
                int gr = rowBase + 16 * m + lrow;
                uint4 u = make_uint4(0, 0, 0, 0);
                if (gr < M) u = *(const uint4*)(h4 + (size_t)gr * 256 + k0);
                ub[cur ^ 1][m] = u;
            }
        }
        MEMFENCE;
        int k0 = 32 * ki + kq;
        const float* sc = stats + 512 + k0;
        const float* sh = stats + 768 + k0;
        bf16x8 af[2];
#pragma unroll
        for (int m = 0; m < 2; ++m) {
            unsigned w[4] = {ub[cur][m].x, ub[cur][m].y, ub[cur][m].z, ub[cur][m].w};
#pragma unroll
            for (int j = 0; j < 4; j++) {
                float lo = fmaxf(bflo(w[j]) * sc[2 * j] + sh[2 * j], 0.f);
                float hi = fmaxf(bfhi(w[j]) * sc[2 * j + 1] + sh[2 * j + 1], 0.f);
                w[j] = ((unsigned)f2bf(hi) << 16) | (unsigned)f2bf(lo);
            }
            uint4 packed = make_uint4(w[0], w[1], w[2], w[3]);
            af[m] = *(const bf16x8*)&packed;
        }
#pragma unroll
        for (int m = 0; m < 2; ++m)
#pragma unroll
            for (int n = 0; n < 2; ++n)
                acc[m][n] = __builtin_amdgcn_mfma_f32_16x16x32_bf16(af[m], Bf[ki][n], acc[m][n], 0, 0, 0);
    }
#pragma unroll
    for (int n = 0; n < 2; ++n) {
        int colg = 16 * n + lrow;
        if (colg >= 18) continue;
        float bb = bias[colg];
#pragma unroll
        for (int m = 0; m < 2; ++m)
#pragma unroll
            for (int r = 0; r < 4; ++r) {
                int rowg = rowBase + 16 * m + lq * 4 + r;
                if (rowg < M)
                    out[(size_t)rowg * 18 + colg] = acc[m][n][r] + bb;
            }
    }
}

// ---------------------------------------------------------------------------
// launch
// ---------------------------------------------------------------------------
extern "C" void kernel_launch(void* const* d_in, const int* in_sizes, int n_in,
                              void* d_out, int out_size, void* d_ws, size_t ws_size,
                              hipStream_t stream) {
    const float* x        = (const float*)d_in[0];
    const int*   edge_row = (const int*)  d_in[1];
    const int*   edge_col = (const int*)  d_in[2];
    const float* edge_val = (const float*)d_in[3];
    const float* gc0_W  = (const float*)d_in[4];
    const float* gc0_b  = (const float*)d_in[5];
    const float* gc0_Ws = (const float*)d_in[6];
    const float* gc0_bs = (const float*)d_in[7];
    const float* gc1_W  = (const float*)d_in[8];
    const float* gc1_b  = (const float*)d_in[9];
    const float* gc1_Ws = (const float*)d_in[10];
    const float* gc1_bs = (const float*)d_in[11];
    const float* gc2_W  = (const float*)d_in[12];
    const float* gc2_b  = (const float*)d_in[13];
    const float* gc2_Ws = (const float*)d_in[14];
    const float* gc2_bs = (const float*)d_in[15];
    const float* fc1_W  = (const float*)d_in[16];
    const float* fc1_b  = (const float*)d_in[17];
    const float* fc2a_W = (const float*)d_in[18];
    const float* fc2a_b = (const float*)d_in[19];
    const float* bn_g   = (const float*)d_in[20];
    const float* bn_b   = (const float*)d_in[21];
    const float* fc2b_W = (const float*)d_in[22];
    const float* fc2b_b = (const float*)d_in[23];
    float* out = (float*)d_out;

    char* ws = (char*)d_ws;
    int*   rowptr = (int*)ws;                          // 400 KB
    float* stats  = (float*)(ws + 512 * 1024);         // 4 KB
    size_t o = 520 * 1024;
    unsigned short* Bt0   = (unsigned short*)(ws + o); o += 200 * 224 * 2;
    unsigned short* Bt1   = (unsigned short*)(ws + o); o += 256 * 224 * 2;
    unsigned short* Bt2   = (unsigned short*)(ws + o); o += 128 * 256 * 2;
    unsigned short* Btf1  = (unsigned short*)(ws + o); o += 128 * 128 * 2;
    unsigned short* Btf2a = (unsigned short*)(ws + o); o += 256 * 128 * 2;
    unsigned short* Btf2b = (unsigned short*)(ws + o); o += 18 * 256 * 2;
    float* bias0 = (float*)(ws + o); o += 200 * 4;
    float* bias2 = (float*)(ws + o); o += 128 * 4;
    float* bias1 = (float*)(ws + o); o += 128 * 4;
    const size_t SLOT = 52u * 1024 * 1024;
    char* S1 = ws + 1 * 1024 * 1024;
    char* S2 = S1 + SLOT;
    char* S3 = S2 + SLOT;

    unsigned short* xb   = (unsigned short*)S1;  // 100k x 104
    unsigned short* agg0 = (unsigned short*)S2;  // 100k x 104
    unsigned short* yz   = (unsigned short*)S3;  // 100k x 256 (y|z)
    unsigned short* h1   = (unsigned short*)S1;  // 100k x 128 (xb dead)
    unsigned short* agg2 = (unsigned short*)S2;  // 100k x 128 (agg0 dead)
    unsigned short* h4   = (unsigned short*)S3;  // 100k x 256 (yz dead)

    // ---- prep ----
    build_row_ptr<<<392, 256, 0, stream>>>(edge_row, rowptr);
    conv_x<<<2048, 256, 0, stream>>>(x, xb);
    prep_all<<<(189128 + 255) / 256, 256, 0, stream>>>(
        gc0_W, gc0_Ws, gc1_W, gc1_Ws, gc2_W, gc2_Ws, fc1_W, fc2a_W, fc2b_W,
        gc0_b, gc0_bs, gc2_b, gc2_bs, gc1_b, gc1_bs,
        Bt0, Bt1, Bt2, Btf1, Btf2a, Btf2b, bias0, bias2, bias1);
    hipMemsetAsync(stats, 0, 512 * sizeof(float), stream);

    const int spmmGrid = N_NODES / 16;  // 6250, exact
    const int tile64 = (N_NODES + 63) / 64;   // 1563

    // ---- GC layer 0 SpMM ----
    spmm_v5<0><<<spmmGrid, 256, 0, stream>>>(xb, 104, 104, rowptr, edge_col, edge_val,
                                             nullptr, agg0, 104);
    // ---- fused head: L0-GEMM + L1-GEMM -> yz ----
    gemm_head<<<tile64, 256, 0, stream>>>(agg0, xb, Bt0, bias0, Bt1, yz, N_NODES);
    // ---- layer-1 SpMM on y + fused combine -> h1 ----
    spmm_v5<1><<<spmmGrid, 256, 0, stream>>>(yz, 256, 128, rowptr, edge_col, edge_val,
                                             bias1, h1, 128);
    // ---- GC layer 2 SpMM ----
    spmm_v5<0><<<spmmGrid, 256, 0, stream>>>(h1, 128, 128, rowptr, edge_col, edge_val,
                                             nullptr, agg2, 128);
    // ---- fused tail: gc2-GEMM + fc1 + fc2a + BN stats ----
    gemm_tail<<<tile64, 256, 0, stream>>>(
        agg2, h1, Bt2, bias2, Btf1, fc1_b, Btf2a, fc2a_b, h4, stats, N_NODES);
    bn_finalize<<<1, 256, 0, stream>>>(stats, bn_g, bn_b);
    // ---- fc2b with fused BN-apply+relu on A ----
    fc2b_kernel<<<(N_NODES + 127) / 128, 256, 0, stream>>>(
        h4, Btf2b, fc2b_b, stats, out, N_NODES);
}

// Round 10
// 508.432 us; speedup vs baseline: 1.0325x; 1.0325x over previous
//
#include <hip/hip_runtime.h>

#define N_NODES 100000
#define N_EDGES 1600000
#define NTILE64 1563
#define LDP 1568

#define MEMFENCE asm volatile("" ::: "memory")

typedef __attribute__((ext_vector_type(8))) short bf16x8;
typedef __attribute__((ext_vector_type(4))) float f32x4;

__device__ __forceinline__ unsigned short f2bf(float f) {
    unsigned u = __float_as_uint(f);
    u = (u + 0x7FFFu + ((u >> 16) & 1u)) >> 16;
    return (unsigned short)u;
}
__device__ __forceinline__ float bf2f(unsigned short h) {
    return __uint_as_float(((unsigned)h) << 16);
}
__device__ __forceinline__ float bflo(unsigned w) { return __uint_as_float(w << 16); }
__device__ __forceinline__ float bfhi(unsigned w) { return __uint_as_float(w & 0xFFFF0000u); }

__device__ __forceinline__ bf16x8 ld_frag(const unsigned short* p) {
    return *(const bf16x8*)p;
}

// ---------------------------------------------------------------------------
// CSR row_ptr via binary search over sorted edge_row
// ---------------------------------------------------------------------------
__global__ void build_row_ptr(const int* __restrict__ row, int* __restrict__ rp) {
    int n = blockIdx.x * blockDim.x + threadIdx.x;
    if (n > N_NODES) return;
    int lo = 0, hi = N_EDGES;
    while (lo < hi) {
        int mid = (lo + hi) >> 1;
        if (row[mid] < n) lo = mid + 1; else hi = mid;
    }
    rp[n] = lo;
}

// ---------------------------------------------------------------------------
// x (fp32, 100k x 100) -> bf16 padded to ld 104
// ---------------------------------------------------------------------------
__global__ __launch_bounds__(256) void conv_x(const float* __restrict__ x,
                                              unsigned short* __restrict__ xb) {
    const int total = N_NODES * 104;
    for (int i = blockIdx.x * 256 + threadIdx.x; i < total; i += gridDim.x * 256) {
        int r = i / 104, c = i - r * 104;
        xb[i] = (c < 100) ? f2bf(x[(size_t)r * 100 + c]) : (unsigned short)0;
    }
}

// ---------------------------------------------------------------------------
// All weight prep in ONE kernel
// ---------------------------------------------------------------------------
__global__ __launch_bounds__(256) void prep_all(
    const float* __restrict__ gc0W, const float* __restrict__ gc0Ws,
    const float* __restrict__ gc1W, const float* __restrict__ gc1Ws,
    const float* __restrict__ gc2W, const float* __restrict__ gc2Ws,
    const float* __restrict__ f1W,  const float* __restrict__ f2aW,
    const float* __restrict__ f2bW,
    const float* __restrict__ gc0b, const float* __restrict__ gc0bs,
    const float* __restrict__ gc2b, const float* __restrict__ gc2bs,
    const float* __restrict__ gc1b, const float* __restrict__ gc1bs,
    unsigned short* __restrict__ Bt0, unsigned short* __restrict__ Bt1,
    unsigned short* __restrict__ Bt2, unsigned short* __restrict__ Btf1,
    unsigned short* __restrict__ Btf2a, unsigned short* __restrict__ Btf2b,
    float* __restrict__ bias0, float* __restrict__ bias2, float* __restrict__ bias1)
{
    int i = blockIdx.x * 256 + threadIdx.x;
    if (i < 44800) {  // Bt0: concat-K (K=100,Kpad=104), N=200, ldk=224
        int n = i / 224, k = i - n * 224; float v = 0.f;
        if (k < 104) { if (k < 100) v = gc0W[(size_t)k * 200 + n]; }
        else { int kr = k - 104; if (kr < 100) v = gc0Ws[(size_t)kr * 200 + n]; }
        Bt0[i] = f2bf(v); return;
    }
    i -= 44800;
    if (i < 57344) {  // Bt1: side-by-side N (K=200, N0=128, N=256), ldk=224
        int n = i / 224, k = i - n * 224; float v = 0.f;
        if (k < 200) v = (n < 128) ? gc1W[(size_t)k * 128 + n] : gc1Ws[(size_t)k * 128 + (n - 128)];
        Bt1[i] = f2bf(v); return;
    }
    i -= 57344;
    if (i < 32768) {  // Bt2: concat-K (K=128), N=128, ldk=256
        int n = i / 256, k = i - n * 256; float v;
        if (k < 128) v = gc2W[(size_t)k * 128 + n];
        else         v = gc2Ws[(size_t)(k - 128) * 128 + n];
        Bt2[i] = f2bf(v); return;
    }
    i -= 32768;
    if (i < 16384) { int n = i >> 7, k = i & 127; Btf1[i] = f2bf(f1W[(size_t)k * 128 + n]); return; }
    i -= 16384;
    if (i < 32768) { int n = i >> 7, k = i & 127; Btf2a[i] = f2bf(f2aW[(size_t)k * 256 + n]); return; }
    i -= 32768;
    if (i < 4608) { int n = i >> 8, k = i & 255; Btf2b[i] = f2bf(f2bW[(size_t)k * 18 + n]); return; }
    i -= 4608;
    if (i < 200) { bias0[i] = gc0b[i] + gc0bs[i]; return; }
    i -= 200;
    if (i < 128) { bias2[i] = gc2b[i] + gc2bs[i]; return; }
    i -= 128;
    if (i < 128) { bias1[i] = gc1b[i] + gc1bs[i]; return; }
}

// ---------------------------------------------------------------------------
// SpMM v4: 16 lanes per node (uint4 = 8 features/lane), 4 nodes/wave.
// FUSE=1: out = relu(agg + z + b01), z at +128.
// ---------------------------------------------------------------------------
template<int FUSE>
__global__ __launch_bounds__(256) void spmm_v4(
    const unsigned short* __restrict__ xin, int ldin, int F,
    const int* __restrict__ rp, const int* __restrict__ col,
    const float* __restrict__ val, const float* __restrict__ b01,
    unsigned short* __restrict__ outp, int ldout)
{
    const int node = blockIdx.x * 16 + (threadIdx.x >> 4);
    const int l16 = threadIdx.x & 15;
    const int f8 = l16 * 8;
    const bool act = f8 < F;
    const int e0 = rp[node], e1 = rp[node + 1];
    const unsigned short* xf = xin + f8;

    float a[8];
#pragma unroll
    for (int k = 0; k < 8; k++) a[k] = 0.f;

    for (int e = e0; e < e1; e += 4) {
        int   cj[4]; float vj[4];
#pragma unroll
        for (int j = 0; j < 4; j++) {
            int ej = e + j;
            bool m = ej < e1;
            int es = m ? ej : e0;
            cj[j] = col[es];
            float vv = val[es];
            vj[j] = m ? vv : 0.f;
        }
        if (act) {
#pragma unroll
            for (int j = 0; j < 4; j++) {
                uint4 u = *(const uint4*)(xf + (size_t)cj[j] * ldin);
                float v = vj[j];
                a[0] += v * bflo(u.x); a[1] += v * bfhi(u.x);
                a[2] += v * bflo(u.y); a[3] += v * bfhi(u.y);
                a[4] += v * bflo(u.z); a[5] += v * bfhi(u.z);
                a[6] += v * bflo(u.w); a[7] += v * bfhi(u.w);
            }
        }
    }

    if (act) {
        if (FUSE) {
            uint4 uz = *(const uint4*)(xin + (size_t)node * ldin + 128 + f8);
            float z[8] = {bflo(uz.x), bfhi(uz.x), bflo(uz.y), bfhi(uz.y),
                          bflo(uz.z), bfhi(uz.z), bflo(uz.w), bfhi(uz.w)};
#pragma unroll
            for (int k = 0; k < 8; k++)
                a[k] = fmaxf(a[k] + z[k] + b01[f8 + k], 0.f);
        }
        uint4 pk;
        pk.x = ((unsigned)f2bf(a[1]) << 16) | (unsigned)f2bf(a[0]);
        pk.y = ((unsigned)f2bf(a[3]) << 16) | (unsigned)f2bf(a[2]);
        pk.z = ((unsigned)f2bf(a[5]) << 16) | (unsigned)f2bf(a[4]);
        pk.w = ((unsigned)f2bf(a[7]) << 16) | (unsigned)f2bf(a[6]);
        *(uint4*)(outp + (size_t)node * ldout + f8) = pk;
    }
}

// ---------------------------------------------------------------------------
// FUSED HEAD v5: B preloaded to registers (chunked) + memory fences.
//   h0 = relu([agg0|xb] @ Bt0 + bias0)  (K=208/pad224, N=200, LDS-resident)
//   yz = h0 @ Bt1                       (K=224, N=256)
// wave w: 64 rows x cols [64w, 64w+64)
// ---------------------------------------------------------------------------
__global__ __launch_bounds__(256) void gemm_head(
    const unsigned short* __restrict__ agg0, const unsigned short* __restrict__ xb,
    const unsigned short* __restrict__ Bt0, const float* __restrict__ bias0,
    const unsigned short* __restrict__ Bt1,
    unsigned short* __restrict__ yz, int M)
{
    __shared__ __align__(16) unsigned short H[64][264];

    const int tid = threadIdx.x;
    const int rowBase = blockIdx.x * 64;
    const int wave = tid >> 6, lane = tid & 63;
    const int cb = wave * 64;
    const int lrow = lane & 15, lq = lane >> 4;
    const int kq = lq * 8;

    // ---------------- stage 1: h0 = relu([agg0|xb]@Bt0 + bias0) ----------
    {
        f32x4 acc[4][4] = {};
        // ---- chunk 0: ki 0..3 ----
        {
            bf16x8 Bf[4][4];
#pragma unroll
            for (int ki = 0; ki < 4; ++ki)
#pragma unroll
                for (int n = 0; n < 4; ++n) {
                    int nr = cb + 16 * n + lrow;
                    bf16x8 t = {};
                    if (nr < 200) t = ld_frag(Bt0 + (size_t)nr * 224 + 32 * ki + kq);
                    Bf[ki][n] = t;
                }
            MEMFENCE;
            bf16x8 A2[2][4];
#pragma unroll
            for (int m = 0; m < 4; ++m) {
                int gr = rowBase + 16 * m + lrow;
                bf16x8 t = {};
                if (gr < M)
                    t = (kq < 104) ? ld_frag(agg0 + (size_t)gr * 104 + kq)
                                   : ld_frag(xb   + (size_t)gr * 104 + (kq - 104));
                A2[0][m] = t;
            }
            MEMFENCE;
#pragma unroll
            for (int ki = 0; ki < 4; ++ki) {
                const int cur = ki & 1;
                if (ki < 3) {
                    int k0 = 32 * (ki + 1) + kq;
#pragma unroll
                    for (int m = 0; m < 4; ++m) {
                        int gr = rowBase + 16 * m + lrow;
                        bf16x8 t = {};
                        if (gr < M)
                            t = (k0 < 104) ? ld_frag(agg0 + (size_t)gr * 104 + k0)
                                           : ld_frag(xb   + (size_t)gr * 104 + (k0 - 104));
                        A2[cur ^ 1][m] = t;
                    }
                }
                MEMFENCE;
#pragma unroll
                for (int m = 0; m < 4; ++m)
#pragma unroll
                    for (int n = 0; n < 4; ++n)
                        acc[m][n] = __builtin_amdgcn_mfma_f32_16x16x32_bf16(A2[cur][m], Bf[ki][n], acc[m][n], 0, 0, 0);
            }
        }
        // ---- chunk 1: ki 4..6 ----
        {
            bf16x8 Bf[3][4];
#pragma unroll
            for (int ki = 0; ki < 3; ++ki)
#pragma unroll
                for (int n = 0; n < 4; ++n) {
                    int nr = cb + 16 * n + lrow;
                    bf16x8 t = {};
                    if (nr < 200) t = ld_frag(Bt0 + (size_t)nr * 224 + 32 * (ki + 4) + kq);
                    Bf[ki][n] = t;
                }
            MEMFENCE;
            bf16x8 A2[2][4];
#pragma unroll
            for (int m = 0; m < 4; ++m) {
                int gr = rowBase + 16 * m + lrow;
                int k0 = 128 + kq;
                bf16x8 t = {};
                if (gr < M && k0 < 208)
                    t = ld_frag(xb + (size_t)gr * 104 + (k0 - 104));
                A2[0][m] = t;
            }
            MEMFENCE;
#pragma unroll
            for (int ki = 0; ki < 3; ++ki) {
                const int cur = ki & 1;
                if (ki < 2) {
                    int k0 = 32 * (ki + 5) + kq;
#pragma unroll
                    for (int m = 0; m < 4; ++m) {
                        int gr = rowBase + 16 * m + lrow;
                        bf16x8 t = {};
                        if (gr < M && k0 < 208)
                            t = ld_frag(xb + (size_t)gr * 104 + (k0 - 104));
                        A2[cur ^ 1][m] = t;
                    }
                }
                MEMFENCE;
#pragma unroll
                for (int m = 0; m < 4; ++m)
#pragma unroll
                    for (int n = 0; n < 4; ++n)
                        acc[m][n] = __builtin_amdgcn_mfma_f32_16x16x32_bf16(A2[cur][m], Bf[ki][n], acc[m][n], 0, 0, 0);
            }
        }
#pragma unroll
        for (int n = 0; n < 4; ++n) {
            int colg = cb + 16 * n + lrow;
            if (colg >= 224) continue;
            float bb = (colg < 200) ? bias0[colg] : 0.f;
#pragma unroll
            for (int m = 0; m < 4; ++m)
#pragma unroll
                for (int r = 0; r < 4; ++r) {
                    int rowl = 16 * m + lq * 4 + r;
                    H[rowl][colg] = f2bf(fmaxf(acc[m][n][r] + bb, 0.f));
                }
        }
    }
    __syncthreads();

    // ---------------- stage 2: yz = h0 @ Bt1 (A from LDS, B preloaded) ------
    {
        f32x4 acc[4][4] = {};
        {
            bf16x8 Bf[4][4];
#pragma unroll
            for (int ki = 0; ki < 4; ++ki)
#pragma unroll
                for (int n = 0; n < 4; ++n)
                    Bf[ki][n] = ld_frag(Bt1 + (size_t)(cb + 16 * n + lrow) * 224 + 32 * ki + kq);
            MEMFENCE;
#pragma unroll
            for (int ki = 0; ki < 4; ++ki) {
                bf16x8 af[4];
#pragma unroll
                for (int m = 0; m < 4; ++m) af[m] = *(const bf16x8*)&H[16 * m + lrow][32 * ki + kq];
#pragma unroll
                for (int m = 0; m < 4; ++m)
#pragma unroll
                    for (int n = 0; n < 4; ++n)
                        acc[m][n] = __builtin_amdgcn_mfma_f32_16x16x32_bf16(af[m], Bf[ki][n], acc[m][n], 0, 0, 0);
            }
        }
        {
            bf16x8 Bf[3][4];
#pragma unroll
            for (int ki = 0; ki < 3; ++ki)
#pragma unroll
                for (int n = 0; n < 4; ++n)
                    Bf[ki][n] = ld_frag(Bt1 + (size_t)(cb + 16 * n + lrow) * 224 + 32 * (ki + 4) + kq);
            MEMFENCE;
#pragma unroll
            for (int ki = 0; ki < 3; ++ki) {
                bf16x8 af[4];
#pragma unroll
                for (int m = 0; m < 4; ++m) af[m] = *(const bf16x8*)&H[16 * m + lrow][32 * (ki + 4) + kq];
#pragma unroll
                for (int m = 0; m < 4; ++m)
#pragma unroll
                    for (int n = 0; n < 4; ++n)
                        acc[m][n] = __builtin_amdgcn_mfma_f32_16x16x32_bf16(af[m], Bf[ki][n], acc[m][n], 0, 0, 0);
            }
        }
        __syncthreads();   // all H reads done before overwrite
#pragma unroll
        for (int n = 0; n < 4; ++n) {
            int colg = cb + 16 * n + lrow;
#pragma unroll
            for (int m = 0; m < 4; ++m)
#pragma unroll
                for (int r = 0; r < 4; ++r) {
                    int rowl = 16 * m + lq * 4 + r;
                    H[rowl][colg] = f2bf(acc[m][n][r]);
                }
        }
    }
    __syncthreads();
    // ---------------- coalesced store: 64 rows x 256 cols, uint4/thread ------
#pragma unroll
    for (int i = 0; i < 8; ++i) {
        int c = tid + 256 * i;           // 0..2047
        int row = c >> 5;                // 0..63
        int ch  = c & 31;                // 0..31 (x8 elements)
        int rowg = rowBase + row;
        if (rowg < M)
            *(uint4*)(yz + (size_t)rowg * 256 + ch * 8) = *(const uint4*)&H[row][ch * 8];
    }
}

// ---------------------------------------------------------------------------
// FUSED TAIL v6: B preloaded + BN partials to per-block buffer (NO atomics).
//   h2 = relu([agg2|h1]@Bt2 + bias2)  (K=256, N=128; wave -> 32 cols)
//   h3 = relu(h2@Btf1 + fc1_b)        (K=128, N=128)
//   h4 = h3@Btf2a + fc2a_b            (K=128, N=256; wave -> 64 cols)
//   BN partial sums -> P[col][block] (each column owned by one wave)
// ---------------------------------------------------------------------------
__global__ __launch_bounds__(256) void gemm_tail(
    const unsigned short* __restrict__ agg2, const unsigned short* __restrict__ h1,
    const unsigned short* __restrict__ Bt2, const float* __restrict__ bias2,
    const unsigned short* __restrict__ Btf1, const float* __restrict__ fc1b,
    const unsigned short* __restrict__ Btf2a, const float* __restrict__ fc2ab,
    unsigned short* __restrict__ h4, float* __restrict__ P, int M)
{
    __shared__ __align__(16) unsigned short H[64][264];

    const int tid = threadIdx.x;
    const int rowBase = blockIdx.x * 64;
    const int wave = tid >> 6, lane = tid & 63;
    const int lrow = lane & 15, lq = lane >> 4;
    const int kq = lq * 8;

    // ---------------- stage 1: h2 = relu([agg2|h1]@Bt2 + bias2) -------------
    {
        const int cb = wave * 32;
        f32x4 acc[4][2] = {};
        bf16x8 Bf[8][2];
#pragma unroll
        for (int ki = 0; ki < 8; ++ki)
#pragma unroll
            for (int n = 0; n < 2; ++n)
                Bf[ki][n] = ld_frag(Bt2 + (size_t)(cb + 16 * n + lrow) * 256 + 32 * ki + kq);
        MEMFENCE;
        bf16x8 A2[2][4];
#pragma unroll
        for (int m = 0; m < 4; ++m) {
            int gr = rowBase + 16 * m + lrow;
            bf16x8 t = {};
            if (gr < M) t = ld_frag(agg2 + (size_t)gr * 128 + kq);
            A2[0][m] = t;
        }
        MEMFENCE;
#pragma unroll
        for (int ki = 0; ki < 8; ++ki) {
            const int cur = ki & 1;
            if (ki < 7) {
                const int kin = ki + 1;
                int k0 = 32 * kin + kq;
                const unsigned short* Asrc = (kin < 4) ? agg2 : h1;
                int krel = (kin < 4) ? k0 : k0 - 128;
#pragma unroll
                for (int m = 0; m < 4; ++m) {
                    int gr = rowBase + 16 * m + lrow;
                    bf16x8 t = {};
                    if (gr < M) t = ld_frag(Asrc + (size_t)gr * 128 + krel);
                    A2[cur ^ 1][m] = t;
                }
            }
            MEMFENCE;
#pragma unroll
            for (int m = 0; m < 4; ++m)
#pragma unroll
                for (int n = 0; n < 2; ++n)
                    acc[m][n] = __builtin_amdgcn_mfma_f32_16x16x32_bf16(A2[cur][m], Bf[ki][n], acc[m][n], 0, 0, 0);
        }
#pragma unroll
        for (int n = 0; n < 2; ++n) {
            int colg = cb + 16 * n + lrow;
            float bb = bias2[colg];
#pragma unroll
            for (int m = 0; m < 4; ++m)
#pragma unroll
                for (int r = 0; r < 4; ++r) {
                    int rowl = 16 * m + lq * 4 + r;
                    H[rowl][colg] = f2bf(fmaxf(acc[m][n][r] + bb, 0.f));
                }
        }
    }
    __syncthreads();

    // ---------------- stage 2: h3 = relu(h2@Btf1 + fc1_b) ----------------
    {
        const int cb = wave * 32;
        f32x4 acc[4][2] = {};
        bf16x8 Bf[4][2];
#pragma unroll
        for (int ki = 0; ki < 4; ++ki)
#pragma unroll
            for (int n = 0; n < 2; ++n)
                Bf[ki][n] = ld_frag(Btf1 + (size_t)(cb + 16 * n + lrow) * 128 + 32 * ki + kq);
        MEMFENCE;
#pragma unroll
        for (int ki = 0; ki < 4; ++ki) {
            bf16x8 af[4];
#pragma unroll
            for (int m = 0; m < 4; ++m) af[m] = *(const bf16x8*)&H[16 * m + lrow][32 * ki + kq];
#pragma unroll
            for (int m = 0; m < 4; ++m)
#pragma unroll
                for (int n = 0; n < 2; ++n)
                    acc[m][n] = __builtin_amdgcn_mfma_f32_16x16x32_bf16(af[m], Bf[ki][n], acc[m][n], 0, 0, 0);
        }
        __syncthreads();   // all reads of h2 done before overwrite
#pragma unroll
        for (int n = 0; n < 2; ++n) {
            int colg = cb + 16 * n + lrow;
            float bb = fc1b[colg];
#pragma unroll
            for (int m = 0; m < 4; ++m)
#pragma unroll
                for (int r = 0; r < 4; ++r) {
                    int rowl = 16 * m + lq * 4 + r;
                    H[rowl][colg] = f2bf(fmaxf(acc[m][n][r] + bb, 0.f));
                }
        }
    }
    __syncthreads();

    // ---------------- stage 3: h4 = h3@Btf2a + fc2a_b + BN partials ----------
    {
        const int cb = wave * 64;
        f32x4 acc[4][4] = {};
        bf16x8 Bf[4][4];
#pragma unroll
        for (int ki = 0; ki < 4; ++ki)
#pragma unroll
            for (int n = 0; n < 4; ++n)
                Bf[ki][n] = ld_frag(Btf2a + (size_t)(cb + 16 * n + lrow) * 128 + 32 * ki + kq);
        MEMFENCE;
#pragma unroll
        for (int ki = 0; ki < 4; ++ki) {
            bf16x8 af[4];
#pragma unroll
            for (int m = 0; m < 4; ++m) af[m] = *(const bf16x8*)&H[16 * m + lrow][32 * ki + kq];
#pragma unroll
            for (int m = 0; m < 4; ++m)
#pragma unroll
                for (int n = 0; n < 4; ++n)
                    acc[m][n] = __builtin_amdgcn_mfma_f32_16x16x32_bf16(af[m], Bf[ki][n], acc[m][n], 0, 0, 0);
        }
        __syncthreads();   // all H (h3) reads done before overwrite

#pragma unroll
        for (int n = 0; n < 4; ++n) {
            int colg = cb + 16 * n + lrow;
            float bb = fc2ab[colg];
            float s = 0.f, s2 = 0.f;
#pragma unroll
            for (int m = 0; m < 4; ++m)
#pragma unroll
                for (int r = 0; r < 4; ++r) {
                    int rowl = 16 * m + lq * 4 + r;
                    float v = acc[m][n][r] + bb;
                    H[rowl][colg] = f2bf(v);
                    if (rowBase + rowl < M) { s += v; s2 += v * v; }
                }
            // reduce over the 4 lanes (lq=0..3) sharing this column
            s  += __shfl_xor(s, 16);  s  += __shfl_xor(s, 32);
            s2 += __shfl_xor(s2, 16); s2 += __shfl_xor(s2, 32);
            if (lq == 0) {
                P[(size_t)colg * LDP + blockIdx.x] = s;
                P[(size_t)(256 + colg) * LDP + blockIdx.x] = s2;
            }
        }
        __syncthreads();
        // coalesced h4 store
#pragma unroll
        for (int i = 0; i < 8; ++i) {
            int c = tid + 256 * i;
            int row = c >> 5;
            int ch  = c & 31;
            int rowg = rowBase + row;
            if (rowg < M)
                *(uint4*)(h4 + (size_t)rowg * 256 + ch * 8) = *(const uint4*)&H[row][ch * 8];
        }
    }
}

// ---------------------------------------------------------------------------
// BN reduce: one block per column; sums P[c][*] and P[256+c][*], computes
// scale/shift into stats[512+c]/stats[768+c].
// ---------------------------------------------------------------------------
__global__ __launch_bounds__(256) void bn_reduce(const float* __restrict__ P,
                                                 const float* __restrict__ g,
                                                 const float* __restrict__ b,
                                                 float* __restrict__ stats) {
    const int c = blockIdx.x;        // 0..255
    const int tid = threadIdx.x;
    __shared__ float r1[256], r2[256];
    float s = 0.f, s2 = 0.f;
    for (int i = tid; i < NTILE64; i += 256) {
        s  += P[(size_t)c * LDP + i];
        s2 += P[(size_t)(256 + c) * LDP + i];
    }
    r1[tid] = s; r2[tid] = s2;
    __syncthreads();
    for (int off = 128; off > 0; off >>= 1) {
        if (tid < off) { r1[tid] += r1[tid + off]; r2[tid] += r2[tid + off]; }
        __syncthreads();
    }
    if (tid == 0) {
        const float invN = 1.f / (float)N_NODES;
        float mu = r1[0] * invN;
        float var = r2[0] * invN - mu * mu;
        float sc = g[c] * rsqrtf(var + 1e-5f);
        stats[512 + c] = sc;
        stats[768 + c] = b[c] - mu * sc;
    }
}

// ---------------------------------------------------------------------------
// fc2b: out = BNrelu(h4) @ Btf2b + fc2b_b (K=256, N=18), B preloaded,
// A 1-deep dbuf with fences. Zero LDS/barriers.
// ---------------------------------------------------------------------------
__global__ __launch_bounds__(256) void fc2b_kernel(
    const unsigned short* __restrict__ h4, const unsigned short* __restrict__ Btf2b,
    const float* __restrict__ bias, const float* __restrict__ stats,
    float* __restrict__ out, int M)
{
    const int tid = threadIdx.x;
    const int wave = tid >> 6, lane = tid & 63;
    const int lrow = lane & 15, lq = lane >> 4;
    const int kq = lq * 8;
    const int rowBase = blockIdx.x * 128 + wave * 32;

    f32x4 acc[2][2] = {};
    bf16x8 Bf[8][2];
#pragma unroll
    for (int ki = 0; ki < 8; ++ki)
#pragma unroll
        for (int n = 0; n < 2; ++n) {
            int nr = 16 * n + lrow;
            bf16x8 t = {};
            if (nr < 18) t = ld_frag(Btf2b + (size_t)nr * 256 + 32 * ki + kq);
            Bf[ki][n] = t;
        }
    MEMFENCE;
    uint4 ub[2][2];
#pragma unroll
    for (int m = 0; m < 2; ++m) {
        int gr = rowBase + 16 * m + lrow;
        uint4 u = make_uint4(0, 0, 0, 0);
        if (gr < M) u = *(const uint4*)(h4 + (size_t)gr * 256 + kq);
        ub[0][m] = u;
    }
    MEMFENCE;
#pragma unroll
    for (int ki = 0; ki < 8; ++ki) {
        const int cur = ki & 1;
        if (ki < 7) {
            int k0 = 32 * (ki + 1) + kq;
#pragma unroll
            for (int m = 0; m < 2; ++m) {
                int gr = rowBase + 16 * m + lrow;
                uint4 u = make_uint4(0, 0, 0, 0);
                if (gr < M) u = *(const uint4*)(h4 + (size_t)gr * 256 + k0);
                ub[cur ^ 1][m] = u;
            }
        }
        MEMFENCE;
        int k0 = 32 * ki + kq;
        const float* sc = stats + 512 + k0;
        const float* sh = stats + 768 + k0;
        bf16x8 af[2];
#pragma unroll
        for (int m = 0; m < 2; ++m) {
            unsigned w[4] = {ub[cur][m].x, ub[cur][m].y, ub[cur][m].z, ub[cur][m].w};
#pragma unroll
            for (int j = 0; j < 4; j++) {
                float lo = fmaxf(bflo(w[j]) * sc[2 * j] + sh[2 * j], 0.f);
                float hi = fmaxf(bfhi(w[j]) * sc[2 * j + 1] + sh[2 * j + 1], 0.f);
                w[j] = ((unsigned)f2bf(hi) << 16) | (unsigned)f2bf(lo);
            }
            uint4 packed = make_uint4(w[0], w[1], w[2], w[3]);
            af[m] = *(const bf16x8*)&packed;
        }
#pragma unroll
        for (int m = 0; m < 2; ++m)
#pragma unroll
            for (int n = 0; n < 2; ++n)
                acc[m][n] = __builtin_amdgcn_mfma_f32_16x16x32_bf16(af[m], Bf[ki][n], acc[m][n], 0, 0, 0);
    }
#pragma unroll
    for (int n = 0; n < 2; ++n) {
        int colg = 16 * n + lrow;
        if (colg >= 18) continue;
        float bb = bias[colg];
#pragma unroll
        for (int m = 0; m < 2; ++m)
#pragma unroll
            for (int r = 0; r < 4; ++r) {
                int rowg = rowBase + 16 * m + lq * 4 + r;
                if (rowg < M)
                    out[(size_t)rowg * 18 + colg] = acc[m][n][r] + bb;
            }
    }
}

// ---------------------------------------------------------------------------
// launch
// ---------------------------------------------------------------------------
extern "C" void kernel_launch(void* const* d_in, const int* in_sizes, int n_in,
                              void* d_out, int out_size, void* d_ws, size_t ws_size,
                              hipStream_t stream) {
    const float* x        = (const float*)d_in[0];
    const int*   edge_row = (const int*)  d_in[1];
    const int*   edge_col = (const int*)  d_in[2];
    const float* edge_val = (const float*)d_in[3];
    const float* gc0_W  = (const float*)d_in[4];
    const float* gc0_b  = (const float*)d_in[5];
    const float* gc0_Ws = (const float*)d_in[6];
    const float* gc0_bs = (const float*)d_in[7];
    const float* gc1_W  = (const float*)d_in[8];
    const float* gc1_b  = (const float*)d_in[9];
    const float* gc1_Ws = (const float*)d_in[10];
    const float* gc1_bs = (const float*)d_in[11];
    const float* gc2_W  = (const float*)d_in[12];
    const float* gc2_b  = (const float*)d_in[13];
    const float* gc2_Ws = (const float*)d_in[14];
    const float* gc2_bs = (const float*)d_in[15];
    const float* fc1_W  = (const float*)d_in[16];
    const float* fc1_b  = (const float*)d_in[17];
    const float* fc2a_W = (const float*)d_in[18];
    const float* fc2a_b = (const float*)d_in[19];
    const float* bn_g   = (const float*)d_in[20];
    const float* bn_b   = (const float*)d_in[21];
    const float* fc2b_W = (const float*)d_in[22];
    const float* fc2b_b = (const float*)d_in[23];
    float* out = (float*)d_out;

    char* ws = (char*)d_ws;
    int*   rowptr = (int*)ws;                          // 400 KB
    float* stats  = (float*)(ws + 512 * 1024);         // 4 KB
    size_t o = 520 * 1024;
    unsigned short* Bt0   = (unsigned short*)(ws + o); o += 200 * 224 * 2;
    unsigned short* Bt1   = (unsigned short*)(ws + o); o += 256 * 224 * 2;
    unsigned short* Bt2   = (unsigned short*)(ws + o); o += 128 * 256 * 2;
    unsigned short* Btf1  = (unsigned short*)(ws + o); o += 128 * 128 * 2;
    unsigned short* Btf2a = (unsigned short*)(ws + o); o += 256 * 128 * 2;
    unsigned short* Btf2b = (unsigned short*)(ws + o); o += 18 * 256 * 2;
    float* bias0 = (float*)(ws + o); o += 200 * 4;
    float* bias2 = (float*)(ws + o); o += 128 * 4;
    float* bias1 = (float*)(ws + o); o += 128 * 4;
    const size_t SLOT = 52u * 1024 * 1024;
    char* S1 = ws + 1 * 1024 * 1024;
    char* S2 = S1 + SLOT;
    char* S3 = S2 + SLOT;

    unsigned short* xb   = (unsigned short*)S1;  // 100k x 104
    unsigned short* agg0 = (unsigned short*)S2;  // 100k x 104
    unsigned short* yz   = (unsigned short*)S3;  // 100k x 256 (y|z)
    unsigned short* h1   = (unsigned short*)S1;  // 100k x 128 (xb dead)
    unsigned short* agg2 = (unsigned short*)S2;  // 100k x 128 (agg0 dead)
    unsigned short* h4   = (unsigned short*)S3;  // 100k x 256 (yz dead)
    float* Pp = (float*)(S2 + 40u * 1024 * 1024);   // 512 x LDP partials (agg2 is 25.6MB)

    // ---- prep ----
    build_row_ptr<<<392, 256, 0, stream>>>(edge_row, rowptr);
    conv_x<<<2048, 256, 0, stream>>>(x, xb);
    prep_all<<<(189128 + 255) / 256, 256, 0, stream>>>(
        gc0_W, gc0_Ws, gc1_W, gc1_Ws, gc2_W, gc2_Ws, fc1_W, fc2a_W, fc2b_W,
        gc0_b, gc0_bs, gc2_b, gc2_bs, gc1_b, gc1_bs,
        Bt0, Bt1, Bt2, Btf1, Btf2a, Btf2b, bias0, bias2, bias1);

    const int spmmGrid = N_NODES / 16;  // 6250, exact

    // ---- GC layer 0 SpMM ----
    spmm_v4<0><<<spmmGrid, 256, 0, stream>>>(xb, 104, 104, rowptr, edge_col, edge_val,
                                             nullptr, agg0, 104);
    // ---- fused head: L0-GEMM + L1-GEMM -> yz ----
    gemm_head<<<NTILE64, 256, 0, stream>>>(agg0, xb, Bt0, bias0, Bt1, yz, N_NODES);
    // ---- layer-1 SpMM on y + fused combine -> h1 ----
    spmm_v4<1><<<spmmGrid, 256, 0, stream>>>(yz, 256, 128, rowptr, edge_col, edge_val,
                                             bias1, h1, 128);
    // ---- GC layer 2 SpMM ----
    spmm_v4<0><<<spmmGrid, 256, 0, stream>>>(h1, 128, 128, rowptr, edge_col, edge_val,
                                             nullptr, agg2, 128);
    // ---- fused tail: gc2-GEMM + fc1 + fc2a + BN partials ----
    gemm_tail<<<NTILE64, 256, 0, stream>>>(
        agg2, h1, Bt2, bias2, Btf1, fc1_b, Btf2a, fc2a_b, h4, Pp, N_NODES);
    // ---- BN reduce (partials -> scale/shift) ----
    bn_reduce<<<256, 256, 0, stream>>>(Pp, bn_g, bn_b, stats);
    // ---- fc2b with fused BN-apply+relu on A ----
    fc2b_kernel<<<(N_NODES + 127) / 128, 256, 0, stream>>>(
        h4, Btf2b, fc2b_b, stats, out, N_NODES);
}

// Round 11
// 490.001 us; speedup vs baseline: 1.0714x; 1.0376x over previous
//
#include <hip/hip_runtime.h>

#define N_NODES 100000
#define N_EDGES 1600000
#define NTILE64 1563
#define LDP 1568

#define MEMFENCE asm volatile("" ::: "memory")

typedef __attribute__((ext_vector_type(8))) short bf16x8;
typedef __attribute__((ext_vector_type(4))) float f32x4;

__device__ __forceinline__ unsigned short f2bf(float f) {
    unsigned u = __float_as_uint(f);
    u = (u + 0x7FFFu + ((u >> 16) & 1u)) >> 16;
    return (unsigned short)u;
}
__device__ __forceinline__ float bf2f(unsigned short h) {
    return __uint_as_float(((unsigned)h) << 16);
}
__device__ __forceinline__ float bflo(unsigned w) { return __uint_as_float(w << 16); }
__device__ __forceinline__ float bfhi(unsigned w) { return __uint_as_float(w & 0xFFFF0000u); }

__device__ __forceinline__ bf16x8 ld_frag(const unsigned short* p) {
    return *(const bf16x8*)p;
}

// ---------------------------------------------------------------------------
// CSR row_ptr via binary search over sorted edge_row
// ---------------------------------------------------------------------------
__global__ void build_row_ptr(const int* __restrict__ row, int* __restrict__ rp) {
    int n = blockIdx.x * blockDim.x + threadIdx.x;
    if (n > N_NODES) return;
    int lo = 0, hi = N_EDGES;
    while (lo < hi) {
        int mid = (lo + hi) >> 1;
        if (row[mid] < n) lo = mid + 1; else hi = mid;
    }
    rp[n] = lo;
}

// ---------------------------------------------------------------------------
// x (fp32, 100k x 100) -> bf16 padded to ld 104
// ---------------------------------------------------------------------------
__global__ __launch_bounds__(256) void conv_x(const float* __restrict__ x,
                                              unsigned short* __restrict__ xb) {
    const int total = N_NODES * 104;
    for (int i = blockIdx.x * 256 + threadIdx.x; i < total; i += gridDim.x * 256) {
        int r = i / 104, c = i - r * 104;
        xb[i] = (c < 100) ? f2bf(x[(size_t)r * 100 + c]) : (unsigned short)0;
    }
}

// ---------------------------------------------------------------------------
// All weight prep in ONE kernel
// ---------------------------------------------------------------------------
__global__ __launch_bounds__(256) void prep_all(
    const float* __restrict__ gc0W, const float* __restrict__ gc0Ws,
    const float* __restrict__ gc1W, const float* __restrict__ gc1Ws,
    const float* __restrict__ gc2W, const float* __restrict__ gc2Ws,
    const float* __restrict__ f1W,  const float* __restrict__ f2aW,
    const float* __restrict__ f2bW,
    const float* __restrict__ gc0b, const float* __restrict__ gc0bs,
    const float* __restrict__ gc2b, const float* __restrict__ gc2bs,
    const float* __restrict__ gc1b, const float* __restrict__ gc1bs,
    unsigned short* __restrict__ Bt0, unsigned short* __restrict__ Bt1,
    unsigned short* __restrict__ Bt2, unsigned short* __restrict__ Btf1,
    unsigned short* __restrict__ Btf2a, unsigned short* __restrict__ Btf2b,
    float* __restrict__ bias0, float* __restrict__ bias2, float* __restrict__ bias1)
{
    int i = blockIdx.x * 256 + threadIdx.x;
    if (i < 44800) {  // Bt0: concat-K (K=100,Kpad=104), N=200, ldk=224
        int n = i / 224, k = i - n * 224; float v = 0.f;
        if (k < 104) { if (k < 100) v = gc0W[(size_t)k * 200 + n]; }
        else { int kr = k - 104; if (kr < 100) v = gc0Ws[(size_t)kr * 200 + n]; }
        Bt0[i] = f2bf(v); return;
    }
    i -= 44800;
    if (i < 57344) {  // Bt1: side-by-side N (K=200, N0=128, N=256), ldk=224
        int n = i / 224, k = i - n * 224; float v = 0.f;
        if (k < 200) v = (n < 128) ? gc1W[(size_t)k * 128 + n] : gc1Ws[(size_t)k * 128 + (n - 128)];
        Bt1[i] = f2bf(v); return;
    }
    i -= 57344;
    if (i < 32768) {  // Bt2: concat-K (K=128), N=128, ldk=256
        int n = i / 256, k = i - n * 256; float v;
        if (k < 128) v = gc2W[(size_t)k * 128 + n];
        else         v = gc2Ws[(size_t)(k - 128) * 128 + n];
        Bt2[i] = f2bf(v); return;
    }
    i -= 32768;
    if (i < 16384) { int n = i >> 7, k = i & 127; Btf1[i] = f2bf(f1W[(size_t)k * 128 + n]); return; }
    i -= 16384;
    if (i < 32768) { int n = i >> 7, k = i & 127; Btf2a[i] = f2bf(f2aW[(size_t)k * 256 + n]); return; }
    i -= 32768;
    if (i < 4608) { int n = i >> 8, k = i & 255; Btf2b[i] = f2bf(f2bW[(size_t)k * 18 + n]); return; }
    i -= 4608;
    if (i < 200) { bias0[i] = gc0b[i] + gc0bs[i]; return; }
    i -= 200;
    if (i < 128) { bias2[i] = gc2b[i] + gc2bs[i]; return; }
    i -= 128;
    if (i < 128) { bias1[i] = gc1b[i] + gc1bs[i]; return; }
}

// ---------------------------------------------------------------------------
// SpMM v4: 16 lanes per node (uint4 = 8 features/lane), 4 nodes/wave.
// FUSE=1: out = relu(agg + z + b01), z at +128.
// ---------------------------------------------------------------------------
template<int FUSE>
__global__ __launch_bounds__(256) void spmm_v4(
    const unsigned short* __restrict__ xin, int ldin, int F,
    const int* __restrict__ rp, const int* __restrict__ col,
    const float* __restrict__ val, const float* __restrict__ b01,
    unsigned short* __restrict__ outp, int ldout)
{
    const int node = blockIdx.x * 16 + (threadIdx.x >> 4);
    const int l16 = threadIdx.x & 15;
    const int f8 = l16 * 8;
    const bool act = f8 < F;
    const int e0 = rp[node], e1 = rp[node + 1];
    const unsigned short* xf = xin + f8;

    float a[8];
#pragma unroll
    for (int k = 0; k < 8; k++) a[k] = 0.f;

    for (int e = e0; e < e1; e += 4) {
        int   cj[4]; float vj[4];
#pragma unroll
        for (int j = 0; j < 4; j++) {
            int ej = e + j;
            bool m = ej < e1;
            int es = m ? ej : e0;
            cj[j] = col[es];
            float vv = val[es];
            vj[j] = m ? vv : 0.f;
        }
        if (act) {
#pragma unroll
            for (int j = 0; j < 4; j++) {
                uint4 u = *(const uint4*)(xf + (size_t)cj[j] * ldin);
                float v = vj[j];
                a[0] += v * bflo(u.x); a[1] += v * bfhi(u.x);
                a[2] += v * bflo(u.y); a[3] += v * bfhi(u.y);
                a[4] += v * bflo(u.z); a[5] += v * bfhi(u.z);
                a[6] += v * bflo(u.w); a[7] += v * bfhi(u.w);
            }
        }
    }

    if (act) {
        if (FUSE) {
            uint4 uz = *(const uint4*)(xin + (size_t)node * ldin + 128 + f8);
            float z[8] = {bflo(uz.x), bfhi(uz.x), bflo(uz.y), bfhi(uz.y),
                          bflo(uz.z), bfhi(uz.z), bflo(uz.w), bfhi(uz.w)};
#pragma unroll
            for (int k = 0; k < 8; k++)
                a[k] = fmaxf(a[k] + z[k] + b01[f8 + k], 0.f);
        }
        uint4 pk;
        pk.x = ((unsigned)f2bf(a[1]) << 16) | (unsigned)f2bf(a[0]);
        pk.y = ((unsigned)f2bf(a[3]) << 16) | (unsigned)f2bf(a[2]);
        pk.z = ((unsigned)f2bf(a[5]) << 16) | (unsigned)f2bf(a[4]);
        pk.w = ((unsigned)f2bf(a[7]) << 16) | (unsigned)f2bf(a[6]);
        *(uint4*)(outp + (size_t)node * ldout + f8) = pk;
    }
}

// ---------------------------------------------------------------------------
// FUSED HEAD (round-7 style: plain direct-load fragments, no fences):
//   h0 = relu([agg0|xb] @ Bt0 + bias0)  (K=208/pad224, N=200, LDS-resident)
//   yz = h0 @ Bt1                       (K=224, N=256)
// wave w: 64 rows x cols [64w, 64w+64)
// ---------------------------------------------------------------------------
__global__ __launch_bounds__(256) void gemm_head(
    const unsigned short* __restrict__ agg0, const unsigned short* __restrict__ xb,
    const unsigned short* __restrict__ Bt0, const float* __restrict__ bias0,
    const unsigned short* __restrict__ Bt1,
    unsigned short* __restrict__ yz, int M)
{
    __shared__ __align__(16) unsigned short H[64][264];

    const int tid = threadIdx.x;
    const int rowBase = blockIdx.x * 64;
    const int wave = tid >> 6, lane = tid & 63;
    const int cb = wave * 64;
    const int lrow = lane & 15, lq = lane >> 4;
    const int kq = lq * 8;

    // ---------------- stage 1: h0 = relu([agg0|xb]@Bt0 + bias0) ----------
    {
        f32x4 acc[4][4] = {};
        for (int kk = 0; kk < 224; kk += 32) {
            int k0 = kk + kq;
            bf16x8 af[4], bfr[4];
#pragma unroll
            for (int m = 0; m < 4; ++m) {
                int gr = rowBase + 16 * m + lrow;
                bf16x8 t = {};
                if (gr < M && k0 < 208)
                    t = (k0 < 104) ? ld_frag(agg0 + (size_t)gr * 104 + k0)
                                   : ld_frag(xb   + (size_t)gr * 104 + (k0 - 104));
                af[m] = t;
            }
#pragma unroll
            for (int n = 0; n < 4; ++n) {
                int nr = cb + 16 * n + lrow;
                bf16x8 t = {};
                if (nr < 200) t = ld_frag(Bt0 + (size_t)nr * 224 + k0);
                bfr[n] = t;
            }
#pragma unroll
            for (int m = 0; m < 4; ++m)
#pragma unroll
                for (int n = 0; n < 4; ++n)
                    acc[m][n] = __builtin_amdgcn_mfma_f32_16x16x32_bf16(af[m], bfr[n], acc[m][n], 0, 0, 0);
        }
#pragma unroll
        for (int n = 0; n < 4; ++n) {
            int colg = cb + 16 * n + lrow;
            if (colg >= 224) continue;
            float bb = (colg < 200) ? bias0[colg] : 0.f;
#pragma unroll
            for (int m = 0; m < 4; ++m)
#pragma unroll
                for (int r = 0; r < 4; ++r) {
                    int rowl = 16 * m + lq * 4 + r;
                    H[rowl][colg] = f2bf(fmaxf(acc[m][n][r] + bb, 0.f));
                }
        }
    }
    __syncthreads();

    // ---------------- stage 2: yz = h0 @ Bt1 ----------------
    {
        f32x4 acc[4][4] = {};
        for (int kk = 0; kk < 224; kk += 32) {
            int k0 = kk + kq;
            bf16x8 af[4], bfr[4];
#pragma unroll
            for (int m = 0; m < 4; ++m) af[m] = *(const bf16x8*)&H[16 * m + lrow][k0];
#pragma unroll
            for (int n = 0; n < 4; ++n)
                bfr[n] = ld_frag(Bt1 + (size_t)(cb + 16 * n + lrow) * 224 + k0);
#pragma unroll
            for (int m = 0; m < 4; ++m)
#pragma unroll
                for (int n = 0; n < 4; ++n)
                    acc[m][n] = __builtin_amdgcn_mfma_f32_16x16x32_bf16(af[m], bfr[n], acc[m][n], 0, 0, 0);
        }
        __syncthreads();   // all H reads done before overwrite
#pragma unroll
        for (int n = 0; n < 4; ++n) {
            int colg = cb + 16 * n + lrow;
#pragma unroll
            for (int m = 0; m < 4; ++m)
#pragma unroll
                for (int r = 0; r < 4; ++r) {
                    int rowl = 16 * m + lq * 4 + r;
                    H[rowl][colg] = f2bf(acc[m][n][r]);
                }
        }
    }
    __syncthreads();
    // ---------------- coalesced store: 64 rows x 256 cols, uint4/thread ------
#pragma unroll
    for (int i = 0; i < 8; ++i) {
        int c = tid + 256 * i;           // 0..2047
        int row = c >> 5;                // 0..63
        int ch  = c & 31;                // 0..31 (x8 elements)
        int rowg = rowBase + row;
        if (rowg < M)
            *(uint4*)(yz + (size_t)rowg * 256 + ch * 8) = *(const uint4*)&H[row][ch * 8];
    }
}

// ---------------------------------------------------------------------------
// FUSED TAIL v6 (round-10: B preloaded + fences, BN partials to P, no atomics)
//   h2 = relu([agg2|h1]@Bt2 + bias2)  (K=256, N=128; wave -> 32 cols)
//   h3 = relu(h2@Btf1 + fc1_b)        (K=128, N=128)
//   h4 = h3@Btf2a + fc2a_b            (K=128, N=256; wave -> 64 cols)
//   BN partial sums -> P[col][block] (each column owned by one wave)
// ---------------------------------------------------------------------------
__global__ __launch_bounds__(256) void gemm_tail(
    const unsigned short* __restrict__ agg2, const unsigned short* __restrict__ h1,
    const unsigned short* __restrict__ Bt2, const float* __restrict__ bias2,
    const unsigned short* __restrict__ Btf1, const float* __restrict__ fc1b,
    const unsigned short* __restrict__ Btf2a, const float* __restrict__ fc2ab,
    unsigned short* __restrict__ h4, float* __restrict__ P, int M)
{
    __shared__ __align__(16) unsigned short H[64][264];

    const int tid = threadIdx.x;
    const int rowBase = blockIdx.x * 64;
    const int wave = tid >> 6, lane = tid & 63;
    const int lrow = lane & 15, lq = lane >> 4;
    const int kq = lq * 8;

    // ---------------- stage 1: h2 = relu([agg2|h1]@Bt2 + bias2) -------------
    {
        const int cb = wave * 32;
        f32x4 acc[4][2] = {};
        bf16x8 Bf[8][2];
#pragma unroll
        for (int ki = 0; ki < 8; ++ki)
#pragma unroll
            for (int n = 0; n < 2; ++n)
                Bf[ki][n] = ld_frag(Bt2 + (size_t)(cb + 16 * n + lrow) * 256 + 32 * ki + kq);
        MEMFENCE;
        bf16x8 A2[2][4];
#pragma unroll
        for (int m = 0; m < 4; ++m) {
            int gr = rowBase + 16 * m + lrow;
            bf16x8 t = {};
            if (gr < M) t = ld_frag(agg2 + (size_t)gr * 128 + kq);
            A2[0][m] = t;
        }
        MEMFENCE;
#pragma unroll
        for (int ki = 0; ki < 8; ++ki) {
            const int cur = ki & 1;
            if (ki < 7) {
                const int kin = ki + 1;
                int k0 = 32 * kin + kq;
                const unsigned short* Asrc = (kin < 4) ? agg2 : h1;
                int krel = (kin < 4) ? k0 : k0 - 128;
#pragma unroll
                for (int m = 0; m < 4; ++m) {
                    int gr = rowBase + 16 * m + lrow;
                    bf16x8 t = {};
                    if (gr < M) t = ld_frag(Asrc + (size_t)gr * 128 + krel);
                    A2[cur ^ 1][m] = t;
                }
            }
            MEMFENCE;
#pragma unroll
            for (int m = 0; m < 4; ++m)
#pragma unroll
                for (int n = 0; n < 2; ++n)
                    acc[m][n] = __builtin_amdgcn_mfma_f32_16x16x32_bf16(A2[cur][m], Bf[ki][n], acc[m][n], 0, 0, 0);
        }
#pragma unroll
        for (int n = 0; n < 2; ++n) {
            int colg = cb + 16 * n + lrow;
            float bb = bias2[colg];
#pragma unroll
            for (int m = 0; m < 4; ++m)
#pragma unroll
                for (int r = 0; r < 4; ++r) {
                    int rowl = 16 * m + lq * 4 + r;
                    H[rowl][colg] = f2bf(fmaxf(acc[m][n][r] + bb, 0.f));
                }
        }
    }
    __syncthreads();

    // ---------------- stage 2: h3 = relu(h2@Btf1 + fc1_b) ----------------
    {
        const int cb = wave * 32;
        f32x4 acc[4][2] = {};
        bf16x8 Bf[4][2];
#pragma unroll
        for (int ki = 0; ki < 4; ++ki)
#pragma unroll
            for (int n = 0; n < 2; ++n)
                Bf[ki][n] = ld_frag(Btf1 + (size_t)(cb + 16 * n + lrow) * 128 + 32 * ki + kq);
        MEMFENCE;
#pragma unroll
        for (int ki = 0; ki < 4; ++ki) {
            bf16x8 af[4];
#pragma unroll
            for (int m = 0; m < 4; ++m) af[m] = *(const bf16x8*)&H[16 * m + lrow][32 * ki + kq];
#pragma unroll
            for (int m = 0; m < 4; ++m)
#pragma unroll
                for (int n = 0; n < 2; ++n)
                    acc[m][n] = __builtin_amdgcn_mfma_f32_16x16x32_bf16(af[m], Bf[ki][n], acc[m][n], 0, 0, 0);
        }
        __syncthreads();   // all reads of h2 done before overwrite
#pragma unroll
        for (int n = 0; n < 2; ++n) {
            int colg = cb + 16 * n + lrow;
            float bb = fc1b[colg];
#pragma unroll
            for (int m = 0; m < 4; ++m)
#pragma unroll
                for (int r = 0; r < 4; ++r) {
                    int rowl = 16 * m + lq * 4 + r;
                    H[rowl][colg] = f2bf(fmaxf(acc[m][n][r] + bb, 0.f));
                }
        }
    }
    __syncthreads();

    // ---------------- stage 3: h4 = h3@Btf2a + fc2a_b + BN partials ----------
    {
        const int cb = wave * 64;
        f32x4 acc[4][4] = {};
        bf16x8 Bf[4][4];
#pragma unroll
        for (int ki = 0; ki < 4; ++ki)
#pragma unroll
            for (int n = 0; n < 4; ++n)
                Bf[ki][n] = ld_frag(Btf2a + (size_t)(cb + 16 * n + lrow) * 128 + 32 * ki + kq);
        MEMFENCE;
#pragma unroll
        for (int ki = 0; ki < 4; ++ki) {
            bf16x8 af[4];
#pragma unroll
            for (int m = 0; m < 4; ++m) af[m] = *(const bf16x8*)&H[16 * m + lrow][32 * ki + kq];
#pragma unroll
            for (int m = 0; m < 4; ++m)
#pragma unroll
                for (int n = 0; n < 4; ++n)
                    acc[m][n] = __builtin_amdgcn_mfma_f32_16x16x32_bf16(af[m], Bf[ki][n], acc[m][n], 0, 0, 0);
        }
        __syncthreads();   // all H (h3) reads done before overwrite

#pragma unroll
        for (int n = 0; n < 4; ++n) {
            int colg = cb + 16 * n + lrow;
            float bb = fc2ab[colg];
            float s = 0.f, s2 = 0.f;
#pragma unroll
            for (int m = 0; m < 4; ++m)
#pragma unroll
                for (int r = 0; r < 4; ++r) {
                    int rowl = 16 * m + lq * 4 + r;
                    float v = acc[m][n][r] + bb;
                    H[rowl][colg] = f2bf(v);
                    if (rowBase + rowl < M) { s += v; s2 += v * v; }
                }
            // reduce over the 4 lanes (lq=0..3) sharing this column
            s  += __shfl_xor(s, 16);  s  += __shfl_xor(s, 32);
            s2 += __shfl_xor(s2, 16); s2 += __shfl_xor(s2, 32);
            if (lq == 0) {
                P[(size_t)colg * LDP + blockIdx.x] = s;
                P[(size_t)(256 + colg) * LDP + blockIdx.x] = s2;
            }
        }
        __syncthreads();
        // coalesced h4 store
#pragma unroll
        for (int i = 0; i < 8; ++i) {
            int c = tid + 256 * i;
            int row = c >> 5;
            int ch  = c & 31;
            int rowg = rowBase + row;
            if (rowg < M)
                *(uint4*)(h4 + (size_t)rowg * 256 + ch * 8) = *(const uint4*)&H[row][ch * 8];
        }
    }
}

// ---------------------------------------------------------------------------
// BN reduce: one block per column; sums P[c][*] and P[256+c][*], computes
// scale/shift into stats[512+c]/stats[768+c].
// ---------------------------------------------------------------------------
__global__ __launch_bounds__(256) void bn_reduce(const float* __restrict__ P,
                                                 const float* __restrict__ g,
                                                 const float* __restrict__ b,
                                                 float* __restrict__ stats) {
    const int c = blockIdx.x;        // 0..255
    const int tid = threadIdx.x;
    __shared__ float r1[256], r2[256];
    float s = 0.f, s2 = 0.f;
    for (int i = tid; i < NTILE64; i += 256) {
        s  += P[(size_t)c * LDP + i];
        s2 += P[(size_t)(256 + c) * LDP + i];
    }
    r1[tid] = s; r2[tid] = s2;
    __syncthreads();
    for (int off = 128; off > 0; off >>= 1) {
        if (tid < off) { r1[tid] += r1[tid + off]; r2[tid] += r2[tid + off]; }
        __syncthreads();
    }
    if (tid == 0) {
        const float invN = 1.f / (float)N_NODES;
        float mu = r1[0] * invN;
        float var = r2[0] * invN - mu * mu;
        float sc = g[c] * rsqrtf(var + 1e-5f);
        stats[512 + c] = sc;
        stats[768 + c] = b[c] - mu * sc;
    }
}

// ---------------------------------------------------------------------------
// fc2b (round-7 style): out = BNrelu(h4) @ Btf2b + fc2b_b (K=256, N=18),
// plain in-loop loads, zero LDS/barriers.
// ---------------------------------------------------------------------------
__global__ __launch_bounds__(256) void fc2b_kernel(
    const unsigned short* __restrict__ h4, const unsigned short* __restrict__ Btf2b,
    const float* __restrict__ bias, const float* __restrict__ stats,
    float* __restrict__ out, int M)
{
    const int tid = threadIdx.x;
    const int wave = tid >> 6, lane = tid & 63;
    const int lrow = lane & 15, lq = lane >> 4;
    const int kq = lq * 8;
    const int rowBase = blockIdx.x * 128 + wave * 32;

    f32x4 acc[2][2] = {};
    for (int kk = 0; kk < 256; kk += 32) {
        int k0 = kk + kq;
        const float* sc = stats + 512 + k0;
        const float* sh = stats + 768 + k0;
        bf16x8 af[2], bfr[2];
#pragma unroll
        for (int m = 0; m < 2; ++m) {
            int gr = rowBase + 16 * m + lrow;
            uint4 u = make_uint4(0, 0, 0, 0);
            if (gr < M) u = *(const uint4*)(h4 + (size_t)gr * 256 + k0);
            unsigned w[4] = {u.x, u.y, u.z, u.w};
#pragma unroll
            for (int j = 0; j < 4; j++) {
                float lo = fmaxf(bflo(w[j]) * sc[2 * j] + sh[2 * j], 0.f);
                float hi = fmaxf(bfhi(w[j]) * sc[2 * j + 1] + sh[2 * j + 1], 0.f);
                w[j] = ((unsigned)f2bf(hi) << 16) | (unsigned)f2bf(lo);
            }
            uint4 packed = make_uint4(w[0], w[1], w[2], w[3]);
            af[m] = *(const bf16x8*)&packed;
        }
#pragma unroll
        for (int n = 0; n < 2; ++n) {
            int nr = 16 * n + lrow;
            bf16x8 t = {};
            if (nr < 18) t = ld_frag(Btf2b + (size_t)nr * 256 + k0);
            bfr[n] = t;
        }
#pragma unroll
        for (int m = 0; m < 2; ++m)
#pragma unroll
            for (int n = 0; n < 2; ++n)
                acc[m][n] = __builtin_amdgcn_mfma_f32_16x16x32_bf16(af[m], bfr[n], acc[m][n], 0, 0, 0);
    }
#pragma unroll
    for (int n = 0; n < 2; ++n) {
        int colg = 16 * n + lrow;
        if (colg >= 18) continue;
        float bb = bias[colg];
#pragma unroll
        for (int m = 0; m < 2; ++m)
#pragma unroll
            for (int r = 0; r < 4; ++r) {
                int rowg = rowBase + 16 * m + lq * 4 + r;
                if (rowg < M)
                    out[(size_t)rowg * 18 + colg] = acc[m][n][r] + bb;
            }
    }
}

// ---------------------------------------------------------------------------
// launch
// ---------------------------------------------------------------------------
extern "C" void kernel_launch(void* const* d_in, const int* in_sizes, int n_in,
                              void* d_out, int out_size, void* d_ws, size_t ws_size,
                              hipStream_t stream) {
    const float* x        = (const float*)d_in[0];
    const int*   edge_row = (const int*)  d_in[1];
    const int*   edge_col = (const int*)  d_in[2];
    const float* edge_val = (const float*)d_in[3];
    const float* gc0_W  = (const float*)d_in[4];
    const float* gc0_b  = (const float*)d_in[5];
    const float* gc0_Ws = (const float*)d_in[6];
    const float* gc0_bs = (const float*)d_in[7];
    const float* gc1_W  = (const float*)d_in[8];
    const float* gc1_b  = (const float*)d_in[9];
    const float* gc1_Ws = (const float*)d_in[10];
    const float* gc1_bs = (const float*)d_in[11];
    const float* gc2_W  = (const float*)d_in[12];
    const float* gc2_b  = (const float*)d_in[13];
    const float* gc2_Ws = (const float*)d_in[14];
    const float* gc2_bs = (const float*)d_in[15];
    const float* fc1_W  = (const float*)d_in[16];
    const float* fc1_b  = (const float*)d_in[17];
    const float* fc2a_W = (const float*)d_in[18];
    const float* fc2a_b = (const float*)d_in[19];
    const float* bn_g   = (const float*)d_in[20];
    const float* bn_b   = (const float*)d_in[21];
    const float* fc2b_W = (const float*)d_in[22];
    const float* fc2b_b = (const float*)d_in[23];
    float* out = (float*)d_out;

    char* ws = (char*)d_ws;
    int*   rowptr = (int*)ws;                          // 400 KB
    float* stats  = (float*)(ws + 512 * 1024);         // 4 KB
    size_t o = 520 * 1024;
    unsigned short* Bt0   = (unsigned short*)(ws + o); o += 200 * 224 * 2;
    unsigned short* Bt1   = (unsigned short*)(ws + o); o += 256 * 224 * 2;
    unsigned short* Bt2   = (unsigned short*)(ws + o); o += 128 * 256 * 2;
    unsigned short* Btf1  = (unsigned short*)(ws + o); o += 128 * 128 * 2;
    unsigned short* Btf2a = (unsigned short*)(ws + o); o += 256 * 128 * 2;
    unsigned short* Btf2b = (unsigned short*)(ws + o); o += 18 * 256 * 2;
    float* bias0 = (float*)(ws + o); o += 200 * 4;
    float* bias2 = (float*)(ws + o); o += 128 * 4;
    float* bias1 = (float*)(ws + o); o += 128 * 4;
    const size_t SLOT = 52u * 1024 * 1024;
    char* S1 = ws + 1 * 1024 * 1024;
    char* S2 = S1 + SLOT;
    char* S3 = S2 + SLOT;

    unsigned short* xb   = (unsigned short*)S1;  // 100k x 104
    unsigned short* agg0 = (unsigned short*)S2;  // 100k x 104
    unsigned short* yz   = (unsigned short*)S3;  // 100k x 256 (y|z)
    unsigned short* h1   = (unsigned short*)S1;  // 100k x 128 (xb dead)
    unsigned short* agg2 = (unsigned short*)S2;  // 100k x 128 (agg0 dead)
    unsigned short* h4   = (unsigned short*)S3;  // 100k x 256 (yz dead)
    float* Pp = (float*)(S2 + 40u * 1024 * 1024);   // 512 x LDP partials (agg2 is 25.6MB)

    // ---- prep ----
    build_row_ptr<<<392, 256, 0, stream>>>(edge_row, rowptr);
    conv_x<<<2048, 256, 0, stream>>>(x, xb);
    prep_all<<<(189128 + 255) / 256, 256, 0, stream>>>(
        gc0_W, gc0_Ws, gc1_W, gc1_Ws, gc2_W, gc2_Ws, fc1_W, fc2a_W, fc2b_W,
        gc0_b, gc0_bs, gc2_b, gc2_bs, gc1_b, gc1_bs,
        Bt0, Bt1, Bt2, Btf1, Btf2a, Btf2b, bias0, bias2, bias1);

    const int spmmGrid = N_NODES / 16;  // 6250, exact

    // ---- GC layer 0 SpMM ----
    spmm_v4<0><<<spmmGrid, 256, 0, stream>>>(xb, 104, 104, rowptr, edge_col, edge_val,
                                             nullptr, agg0, 104);
    // ---- fused head: L0-GEMM + L1-GEMM -> yz ----
    gemm_head<<<NTILE64, 256, 0, stream>>>(agg0, xb, Bt0, bias0, Bt1, yz, N_NODES);
    // ---- layer-1 SpMM on y + fused combine -> h1 ----
    spmm_v4<1><<<spmmGrid, 256, 0, stream>>>(yz, 256, 128, rowptr, edge_col, edge_val,
                                             bias1, h1, 128);
    // ---- GC layer 2 SpMM ----
    spmm_v4<0><<<spmmGrid, 256, 0, stream>>>(h1, 128, 128, rowptr, edge_col, edge_val,
                                             nullptr, agg2, 128);
    // ---- fused tail: gc2-GEMM + fc1 + fc2a + BN partials ----
    gemm_tail<<<NTILE64, 256, 0, stream>>>(
        agg2, h1, Bt2, bias2, Btf1, fc1_b, Btf2a, fc2a_b, h4, Pp, N_NODES);
    // ---- BN reduce (partials -> scale/shift) ----
    bn_reduce<<<256, 256, 0, stream>>>(Pp, bn_g, bn_b, stats);
    // ---- fc2b with fused BN-apply+relu on A ----
    fc2b_kernel<<<(N_NODES + 127) / 128, 256, 0, stream>>>(
        h4, Btf2b, fc2b_b, stats, out, N_NODES);
}